// Round 16
// baseline (91.674 us; speedup 1.0000x reference)
//
#include <hip/hip_runtime.h>

// Problem constants
#define EMBED 1024
#define NHEAD 16
#define HD    64
#define SEQ   2048
#define BATCH 2
#define ROWS  (BATCH * SEQ)  // 4096

typedef float f32x4 __attribute__((ext_vector_type(4)));
typedef short short8 __attribute__((ext_vector_type(8)));
typedef short short4v __attribute__((ext_vector_type(4)));
typedef unsigned short u16x4 __attribute__((ext_vector_type(4)));
typedef unsigned short u16x8 __attribute__((ext_vector_type(8)));
typedef unsigned u32x4 __attribute__((ext_vector_type(4)));
typedef unsigned u32x2 __attribute__((ext_vector_type(2)));

#define LOG2E 1.4426950408889634f

__device__ __forceinline__ unsigned short f2bf(float f) {
  unsigned int u = __builtin_bit_cast(unsigned int, f);
  u += 0x7fffu + ((u >> 16) & 1u);  // round-to-nearest-even
  return (unsigned short)(u >> 16);
}

// pack 2 f32 -> 2 bf16 in one u32 (RNE), gfx950
__device__ __forceinline__ unsigned cvtpk(float lo, float hi) {
  unsigned r;
  asm("v_cvt_pk_bf16_f32 %0, %1, %2" : "=v"(r) : "v"(lo), "v"(hi));
  return r;
}

#if __has_builtin(__builtin_amdgcn_exp2f)
#define EXP2(x) __builtin_amdgcn_exp2f(x)
#else
#define EXP2(x) exp2f(x)
#endif

__device__ __forceinline__ void gll16(const void* g, const void* l) {
  __builtin_amdgcn_global_load_lds(
      (const __attribute__((address_space(1))) unsigned int*)g,
      (__attribute__((address_space(3))) unsigned int*)l, 16, 0, 0);
}

__device__ __forceinline__ unsigned lds_addr(const void* p) {
  return (unsigned)(size_t)(__attribute__((address_space(3))) const void*)p;
}

// ---------------------------------------------------------------- cvt (u16x8 vectorized, 16B stores)
// 4 weights (y<4), x->bf16 (y==4), Wf hi+lo + qkmax zero (y==5)
__global__ __launch_bounds__(256) void cvt_all_kernel(
    const float* __restrict__ x,
    const float* __restrict__ w0, const float* __restrict__ w1,
    const float* __restrict__ w2, const float* __restrict__ w3,
    const float* __restrict__ wf,
    unsigned short* __restrict__ xo,
    unsigned short* __restrict__ o0, unsigned short* __restrict__ o1,
    unsigned short* __restrict__ o2, unsigned short* __restrict__ o3,
    unsigned short* __restrict__ wfh, unsigned short* __restrict__ wfl,
    unsigned* __restrict__ qkmaxu) {
  const int y = blockIdx.y;
  if (y < 4) {
    const float* in = (y == 0) ? w0 : (y == 1) ? w1 : (y == 2) ? w2 : w3;
    unsigned short* out = (y == 0) ? o0 : (y == 1) ? o1 : (y == 2) ? o2 : o3;
    const int i = blockIdx.x * 256 + threadIdx.x;  // u16x8 index, 131072 per weight
    const f32x4 v0 = reinterpret_cast<const f32x4*>(in)[2 * i];
    const f32x4 v1 = reinterpret_cast<const f32x4*>(in)[2 * i + 1];
    u16x8 o;
#pragma unroll
    for (int e = 0; e < 4; ++e) { o[e] = f2bf(v0[e]); o[e + 4] = f2bf(v1[e]); }
    reinterpret_cast<u16x8*>(out)[i] = o;
  } else if (y == 4) {
#pragma unroll
    for (int e = 0; e < 4; ++e) {
      const int i = e * 131072 + blockIdx.x * 256 + threadIdx.x;  // u16x8 index, 524288 total
      const f32x4 v0 = reinterpret_cast<const f32x4*>(x)[2 * i];
      const f32x4 v1 = reinterpret_cast<const f32x4*>(x)[2 * i + 1];
      u16x8 h;
#pragma unroll
      for (int q = 0; q < 4; ++q) { h[q] = f2bf(v0[q]); h[q + 4] = f2bf(v1[q]); }
      reinterpret_cast<u16x8*>(xo)[i] = h;
    }
  } else {
    if (blockIdx.x < 8) {
      const int i = blockIdx.x * 256 + threadIdx.x;  // u16x8 index, 2048 total
      const f32x4 v0 = reinterpret_cast<const f32x4*>(wf)[2 * i];
      const f32x4 v1 = reinterpret_cast<const f32x4*>(wf)[2 * i + 1];
      u16x8 h, l;
#pragma unroll
      for (int q = 0; q < 4; ++q) {
        h[q] = f2bf(v0[q]);
        l[q] = f2bf(v0[q] - __builtin_bit_cast(float, (unsigned)h[q] << 16));
        h[q + 4] = f2bf(v1[q]);
        l[q + 4] = f2bf(v1[q] - __builtin_bit_cast(float, (unsigned)h[q + 4] << 16));
      }
      reinterpret_cast<u16x8*>(wfh)[i] = h;
      reinterpret_cast<u16x8*>(wfl)[i] = l;
    } else if (blockIdx.x == 8) {
      if (threadIdx.x < 64) qkmaxu[threadIdx.x] = 0u;  // zero-init for atomicMax (workspace is poisoned)
    }
  }
}

// ---------------------------------------------------------------- Wo GEMM C = A @ B^T, 64x64 tile, BK=64, fp32 out
// R16: DOUBLE-BUFFERED (fa_attn prefetch pattern): stage t+1 issued BEFORE compute of t; the
// trailing __syncthreads' compiler-emitted vmcnt(0) drain covers the prefetch. One barrier/iter
// (was two + exposed stage latency). LDS 32KB -> still 4 blocks/CU.
__global__ __launch_bounds__(256) void gemm_wo_kernel(
    const unsigned short* __restrict__ A, const unsigned short* __restrict__ B,
    float* __restrict__ C) {
  __shared__ unsigned short Asm[2][64 * 64];
  __shared__ unsigned short Bsm[2][64 * 64];
  const int tid = threadIdx.x, wid = tid >> 6, lane = tid & 63;
  const int g = lane >> 4, l16 = lane & 15;
  const int wr = wid >> 1, wc = wid & 1;  // wave tile: rows wr*32, cols wc*32
  const int mb = blockIdx.y;              // 64-row tiles (64)
  const int nb = blockIdx.x;              // 64-col tiles (16)

  f32x4 acc[2][2] = {};

#define WOSTAGE(bufi_, k0_)                                                       \
  do {                                                                            \
    _Pragma("unroll") for (int q = 0; q < 2; ++q) {                               \
      const int base_ = (wid * 2 + q) * 1024;                                     \
      const int off_ = base_ + lane * 16;                                         \
      const int row_ = off_ >> 7;                                                 \
      const int colel_ = (off_ & 127) >> 1;                                       \
      gll16(A + (size_t)(mb * 64 + row_) * EMBED + (k0_) + colel_,                \
            (const char*)&Asm[bufi_][0] + base_);                                 \
      gll16(B + (size_t)(nb * 64 + row_) * EMBED + (k0_) + colel_,                \
            (const char*)&Bsm[bufi_][0] + base_);                                 \
    }                                                                             \
  } while (0)

  WOSTAGE(0, 0);
  __syncthreads();  // vmcnt(0) drain + barrier: tile 0 resident
  int buf = 0;
  for (int t = 0; t < 16; ++t) {
    if (t < 15) WOSTAGE(buf ^ 1, (t + 1) * 64);  // prefetch under compute
#pragma unroll
    for (int kc = 0; kc < 2; ++kc) {
      short8 am[2], bm[2];
#pragma unroll
      for (int mi = 0; mi < 2; ++mi)
        am[mi] = *reinterpret_cast<const short8*>(&Asm[buf][(wr * 32 + mi * 16 + l16) * 64 + kc * 32 + g * 8]);
#pragma unroll
      for (int ni = 0; ni < 2; ++ni)
        bm[ni] = *reinterpret_cast<const short8*>(&Bsm[buf][(wc * 32 + ni * 16 + l16) * 64 + kc * 32 + g * 8]);
#pragma unroll
      for (int mi = 0; mi < 2; ++mi)
#pragma unroll
        for (int ni = 0; ni < 2; ++ni)
          acc[mi][ni] = __builtin_amdgcn_mfma_f32_16x16x32_bf16(am[mi], bm[ni], acc[mi][ni], 0, 0, 0);
    }
    if (t < 15) __syncthreads();  // drains prefetch vmcnt + all waves' reads of buf
    buf ^= 1;
  }
#undef WOSTAGE

#pragma unroll
  for (int mi = 0; mi < 2; ++mi)
#pragma unroll
    for (int ni = 0; ni < 2; ++ni)
#pragma unroll
      for (int r = 0; r < 4; ++r) {
        const int m = mb * 64 + wr * 32 + mi * 16 + g * 4 + r;
        const int n = nb * 64 + wc * 32 + ni * 16 + l16;
        C[(size_t)m * EMBED + n] = acc[mi][ni][r];
      }
}

// ---------------------------------------------------------------- 256x256 8-phase GEMM + FUSED GATE
// Blocks 0..191: QKV GEMM (best measured of 3 structures; parked). Blocks 192..255: gate.
#define BAR() asm volatile("s_barrier" ::: "memory")
#define LGKM0()                                              \
  do {                                                       \
    asm volatile("s_waitcnt lgkmcnt(0)" ::: "memory");       \
    __builtin_amdgcn_sched_barrier(0);                       \
  } while (0)
#define VM(n_) asm volatile("s_waitcnt vmcnt(" #n_ ")" ::: "memory")

__global__ __launch_bounds__(512, 2) void gemm256_kernel(
    const unsigned short* __restrict__ A,
    const unsigned short* __restrict__ B0, const unsigned short* __restrict__ B1,
    const unsigned short* __restrict__ B2,
    unsigned short* __restrict__ C0, unsigned short* __restrict__ C1,
    unsigned short* __restrict__ C2, unsigned* __restrict__ qkmaxu,
    const float* __restrict__ x, const unsigned short* __restrict__ wfh,
    const unsigned short* __restrict__ wfl, float* __restrict__ carr) {
  __shared__ unsigned short sm[2][2][2][8192];  // [dbuf][AB][half][row*64+col] : 128 KiB
  const int tid = threadIdx.x, wid = tid >> 6, lane = tid & 63;
  const int g = lane >> 4, l16 = lane & 15;

  if (blockIdx.x >= 192) {
    // ---------------- gate branch (runs on the 64 CUs the GEMM grid leaves idle) ----------------
    const int bid2 = blockIdx.x - 192;           // 0..63
    const int tile = bid2 * 4 + (wid >> 1);      // 0..255 (16-row tiles)
    const int half = wid & 1;                    // 2-way split-K
    const int row0 = tile * 16;
    const int k0 = half * 512;
    const float* xp = x + (size_t)(row0 + l16) * EMBED + k0 + g * 8;
    const unsigned short* whp = wfh + (size_t)l16 * EMBED + k0 + g * 8;
    const unsigned short* wlp = wfl + (size_t)l16 * EMBED + k0 + g * 8;
    f32x4 acc = {};
#pragma unroll
    for (int k = 0; k < 16; ++k) {
      const f32x4 v0 = *reinterpret_cast<const f32x4*>(xp + k * 32);
      const f32x4 v1 = *reinterpret_cast<const f32x4*>(xp + k * 32 + 4);
      short8 ah, al;
#pragma unroll
      for (int e = 0; e < 4; ++e) {
        const unsigned short h0 = f2bf(v0[e]);
        ah[e] = (short)h0;
        al[e] = (short)f2bf(v0[e] - __builtin_bit_cast(float, (unsigned)h0 << 16));
        const unsigned short h1 = f2bf(v1[e]);
        ah[e + 4] = (short)h1;
        al[e + 4] = (short)f2bf(v1[e] - __builtin_bit_cast(float, (unsigned)h1 << 16));
      }
      const short8 bh = *reinterpret_cast<const short8*>(whp + k * 32);
      const short8 bl = *reinterpret_cast<const short8*>(wlp + k * 32);
      acc = __builtin_amdgcn_mfma_f32_16x16x32_bf16(ah, bh, acc, 0, 0, 0);
      acc = __builtin_amdgcn_mfma_f32_16x16x32_bf16(ah, bl, acc, 0, 0, 0);
      acc = __builtin_amdgcn_mfma_f32_16x16x32_bf16(al, bh, acc, 0, 0, 0);
    }
    f32x4* red = reinterpret_cast<f32x4*>(sm);  // alias: [8][64] f32x4 = 8KB of the 128KB
    red[wid * 64 + lane] = acc;
    __syncthreads();
    if (half == 0) {
      const f32x4 a = red[wid * 64 + lane] + red[(wid + 1) * 64 + lane];
#pragma unroll
      for (int r = 0; r < 4; ++r) {
        const float s = a[r];
        const float ls = (fminf(s, 0.f) - log1pf(__expf(-fabsf(s)))) * LOG2E;
        const int n = row0 + g * 4 + r;
        const int b = n >> 11, nn = n & (SEQ - 1);
        carr[(size_t)(b * NHEAD + l16) * SEQ + nn] = ls;
      }
    }
    return;
  }

  // ---------------- GEMM branch (blocks 0..191) ----------------
  const int wr = wid >> 2, wcol = wid & 3;  // wave tile: rows wr*128.. , cols wcol*64..
  const int mb = blockIdx.x / 12;
  const int nb = blockIdx.x % 12;  // which = nb>>2, col0 = (nb&3)*256
  const int which = nb >> 2;
  const int col0 = (nb & 3) * 256;
  const unsigned short* Bp = (which == 0) ? B0 : (which == 1) ? B1 : B2;
  unsigned short* Cp = (which == 0) ? C0 : (which == 1) ? C1 : C2;

  // ---- staging invariants (pre-swizzled global source, linear LDS dest) ----
  const int lane8 = lane & 7, laneHi = lane >> 3;
  const int colel = (lane8 ^ laneHi) * 8;  // source col element (inverse swizzle; row&7 == laneHi)
  int soff[2];
#pragma unroll
  for (int q = 0; q < 2; ++q)
    soff[q] = (q * 64 + wid * 8 + laneHi) * EMBED + colel;  // element offset within a half-panel
  const unsigned short* Ag = A + (size_t)(mb * 256) * EMBED;
  const unsigned short* Bg = Bp + (size_t)col0 * EMBED;

  // ---- ds_read invariants (swizzled column offsets; row&7 == l16&7 for all frag rows) ----
  const int sw = (l16 & 7) << 4;
  const int cs0 = (0 | (g * 16)) ^ sw;   // kc=0
  const int cs1 = (64 | (g * 16)) ^ sw;  // kc=1
  const char* smB = (const char*)sm;
  const int aBase = wr * 16384 + l16 * 128;
  const int bBase = 32768 + (wcol >> 1) * 16384 + (wcol & 1) * 8192 + l16 * 128;

#define STG(buf_, ab_, half_, gsrc_, t_)                                               \
  do {                                                                                 \
    const unsigned short* gp_ = (gsrc_) + (size_t)(half_) * (128 * EMBED) + (t_) * 64; \
    char* lp_ = (char*)sm + (buf_) * 65536 + (ab_) * 32768 + (half_) * 16384 + wid * 1024; \
    gll16(gp_ + soff[0], lp_);                                                         \
    gll16(gp_ + soff[1], lp_ + 8192);                                                  \
  } while (0)

#define RD_A(buf_, row_, kc_) \
  (*reinterpret_cast<const short8*>(smB + (buf_) * 65536 + aBase + (row_) * 2048 + ((kc_) ? cs1 : cs0)))
#define RD_B(buf_, row_, kc_) \
  (*reinterpret_cast<const short8*>(smB + (buf_) * 65536 + bBase + (row_) * 2048 + ((kc_) ? cs1 : cs0)))

#define QUAD(mg_, ng_)                                                                   \
  do {                                                                                   \
    __builtin_amdgcn_s_setprio(1);                                                       \
    _Pragma("unroll") for (int kc_ = 0; kc_ < 2; ++kc_)                                  \
      _Pragma("unroll") for (int mi_ = 0; mi_ < 4; ++mi_)                                \
        _Pragma("unroll") for (int nj_ = 0; nj_ < 2; ++nj_)                              \
          acc[(mg_) * 4 + mi_][(ng_) * 2 + nj_] = __builtin_amdgcn_mfma_f32_16x16x32_bf16( \
              fa[mi_][kc_], fb[(ng_) * 2 + nj_][kc_], acc[(mg_) * 4 + mi_][(ng_) * 2 + nj_], 0, 0, 0); \
    __builtin_amdgcn_s_setprio(0);                                                       \
  } while (0)

  // 4 phases of one K-tile: ph1 {12 ds_reads, stage, Q(0,0)}, ph2 {4, stage, Q(0,1)},
  // ph3 {8, stage, Q(1,0)}, ph4 {stage+vmcnt, Q(1,1)}
#define KTILE4(BUF_, STG_P1, STG_P2, STG_P3, STG_P4_VM)                                  \
  do {                                                                                   \
    _Pragma("unroll") for (int mi_ = 0; mi_ < 4; ++mi_) {                                \
      fa[mi_][0] = RD_A(BUF_, mi_, 0);                                                   \
      fa[mi_][1] = RD_A(BUF_, mi_, 1);                                                   \
    }                                                                                    \
    _Pragma("unroll") for (int ni_ = 0; ni_ < 2; ++ni_) {                                \
      fb[ni_][0] = RD_B(BUF_, ni_, 0);                                                   \
      fb[ni_][1] = RD_B(BUF_, ni_, 1);                                                   \
    }                                                                                    \
    STG_P1;                                                                              \
    asm volatile("s_waitcnt lgkmcnt(8)" ::: "memory");                                   \
    BAR();                                                                               \
    LGKM0();                                                                             \
    QUAD(0, 0);                                                                          \
    BAR();                                                                               \
    _Pragma("unroll") for (int ni_ = 0; ni_ < 2; ++ni_) {                                \
      fb[2 + ni_][0] = RD_B(BUF_, 2 + ni_, 0);                                           \
      fb[2 + ni_][1] = RD_B(BUF_, 2 + ni_, 1);                                           \
    }                                                                                    \
    STG_P2;                                                                              \
    BAR();                                                                               \
    LGKM0();                                                                             \
    QUAD(0, 1);                                                                          \
    BAR();                                                                               \
    _Pragma("unroll") for (int mi_ = 0; mi_ < 4; ++mi_) {                                \
      fa[mi_][0] = RD_A(BUF_, 4 + mi_, 0);                                               \
      fa[mi_][1] = RD_A(BUF_, 4 + mi_, 1);                                               \
    }                                                                                    \
    STG_P3;                                                                              \
    BAR();                                                                               \
    LGKM0();                                                                             \
    QUAD(1, 0);                                                                          \
    BAR();                                                                               \
    STG_P4_VM;                                                                           \
    BAR();                                                                               \
    QUAD(1, 1);                                                                          \
    BAR();                                                                               \
  } while (0)

  short8 fa[4][2], fb[4][2];
  f32x4 acc[8][4] = {};

  // ---- prologue: tile0 fully (A0,B0,A1,B1) + tile1 B-halves; wait tile0, keep 2 halves in flight ----
  STG(0, 0, 0, Ag, 0);
  STG(0, 1, 0, Bg, 0);
  STG(0, 0, 1, Ag, 0);
  STG(0, 1, 1, Bg, 0);
  STG(1, 1, 0, Bg, 1);
  STG(1, 1, 1, Bg, 1);
  VM(4);
  BAR();

  // ---- main loop: 16 K-tiles, 2 per iteration (buf0 then buf1), 8 phases ----
  for (int it = 0; it < 8; ++it) {
    const int t1 = 2 * it + 1, t2 = 2 * it + 2, t3 = 2 * it + 3;
    const bool nl = (it < 7);
    // K-tile 2i (buf0); stage t1's A-halves (buf1) then t2's B-halves (buf0, released after ph2)
    KTILE4(0,
           STG(1, 0, 0, Ag, t1),
           STG(1, 0, 1, Ag, t1),
           if (nl) STG(0, 1, 0, Bg, t2),
           if (nl) { STG(0, 1, 1, Bg, t2); VM(4); } else VM(0));
    // K-tile 2i+1 (buf1); stage t2's A-halves (buf0, released after ph3) then t3's B-halves (buf1)
    KTILE4(1,
           if (nl) STG(0, 0, 0, Ag, t2),
           if (nl) STG(0, 0, 1, Ag, t2),
           if (nl) STG(1, 1, 0, Bg, t3),
           if (nl) { STG(1, 1, 1, Bg, t3); VM(4); });
  }

  // ---- epilogue (+ fused maxabs for Q/K tensors) ----
  unsigned mxv = 0;
#pragma unroll
  for (int mi = 0; mi < 8; ++mi)
#pragma unroll
    for (int ni = 0; ni < 4; ++ni)
#pragma unroll
      for (int r = 0; r < 4; ++r) {
        const int m = mb * 256 + wr * 128 + mi * 16 + g * 4 + r;
        const int n = col0 + wcol * 64 + ni * 16 + l16;
        const unsigned short bv = f2bf(acc[mi][ni][r]);
        Cp[(size_t)m * EMBED + n] = bv;
        const unsigned a = bv & 0x7fffu;
        mxv = a > mxv ? a : mxv;
      }
  if (which < 2) {
#pragma unroll
    for (int mm = 1; mm < 64; mm <<= 1) {
      const unsigned o = __shfl_xor(mxv, mm);
      mxv = o > mxv ? o : mxv;
    }
    if (lane == 0) {
      const int bbat = (mb >= 8) ? 1 : 0;
      const int head = (nb & 3) * 4 + wcol;
      const int idx = which * 32 + bbat * 16 + head;
      atomicMax(&qkmaxu[idx], mxv << 16);  // positive-float bits: uint max == float max
    }
  }
#undef STG
#undef RD_A
#undef RD_B
#undef QUAD
#undef KTILE4
}
#undef BAR
#undef LGKM0
#undef VM

// ---------------------------------------------------------------- cumsum per (b,h) + decay-skip table
__global__ void cumsum_kernel(float* __restrict__ c, const float* __restrict__ qkmax,
                              int* __restrict__ tstart) {
  __shared__ float tendS[32];    // tendS[t-1] = c2[t*64-1]
  __shared__ float cfirstS[32];  // cfirstS[qb] = c2[qb*64]
  const int bh = blockIdx.x;
  const int lane = threadIdx.x;  // 64
  float* p = c + (size_t)bh * SEQ;
  f32x4 vv[8];
  f32x4* vp = reinterpret_cast<f32x4*>(p + lane * 32);
#pragma unroll
  for (int q = 0; q < 8; ++q) vv[q] = vp[q];
  float run = 0.f;
#pragma unroll
  for (int q = 0; q < 8; ++q)
#pragma unroll
    for (int e = 0; e < 4; ++e) { run += vv[q][e]; vv[q][e] = run; }
  float s = run;
#pragma unroll
  for (int off = 1; off < 64; off <<= 1) {
    float u = __shfl_up(s, off);
    if (lane >= off) s += u;
  }
  const float excl = s - run;
#pragma unroll
  for (int q = 0; q < 8; ++q)
#pragma unroll
    for (int e = 0; e < 4; ++e) vv[q][e] += excl;
#pragma unroll
  for (int q = 0; q < 8; ++q) vp[q] = vv[q];

  // decay-skip table
  if (lane & 1) tendS[lane >> 1] = s;            // lane 2t-1 -> tendS[t-1], t=1..32
  else cfirstS[lane >> 1] = vv[0][0];            // lane 2qb  -> cfirstS[qb]
  __syncthreads();
  if (lane < 32) {
    const float qm = qkmax[bh];
    const float km = qkmax[32 + bh];
    const float thr = -41.f - 23.0832f * qm * km;  // -41 - 2U, U = 64*0.125*LOG2E*qm*km
    const float c2imin = cfirstS[lane];
    int t = lane;
    while (t > 0 && (c2imin - tendS[t - 1] >= thr)) --t;
    tstart[bh * 32 + lane] = t;
  }
}

// ---------------------------------------------------------------- flash attention, swapped-QK^T, XCD-clustered
#define NINF (-3.0e38f)
#define SCL (0.125f * LOG2E)
#define BMARG 14.0f

#define TR_READ(dst, addr, OFF) \
  asm volatile("ds_read_b64_tr_b16 %0, %1 offset:" OFF : "=v"(dst) : "v"(addr))

__global__ __launch_bounds__(256) void fa_attn_kernel(
    const unsigned short* __restrict__ Q, const unsigned short* __restrict__ K,
    const unsigned short* __restrict__ V, const float* __restrict__ C,
    const int* __restrict__ tstartTab, unsigned short* __restrict__ O) {
  __shared__ unsigned short Ksm[2][4096];  // 8KB each: [64 j][64 dh], rows XOR-swizzled
  __shared__ unsigned short Vsm[2][4096];  // 8KB each: [4 dblk][64 j][16 d] subtiled
  const int p = blockIdx.x;                 // 0..1023
  const int xcd = p & 7, s2 = p >> 3;       // 128 blocks per XCD
  const int hb = xcd * 4 + (s2 >> 5);       // (b,h) pair index (4 per XCD -> 2MB L2 set)
  const int qb = s2 & 31;
  const int hh = hb & 15, bb = hb >> 4;
  const int tid = threadIdx.x, wid = tid >> 6, lane = tid & 63;
  const int g = lane >> 4, l16 = lane & 15;
  const int i_base = qb * 64 + wid * 16;

  const float* cptr = C + (size_t)(bb * NHEAD + hh) * SEQ;

  // staging source offsets (elements, relative to tile origin), per lane
  int kOff[2], vOff[2];
#pragma unroll
  for (int qq = 0; qq < 2; ++qq) {
    const int q = wid * 2 + qq;
    {  // K: linear LDS pos pl = q*1024 + lane*16 -> row = pl>>7, swizzled source col
      const int row = q * 8 + (lane >> 3);
      const int colel = ((lane & 7) ^ (lane >> 3)) * 8;
      kOff[qq] = row * EMBED + colel;
    }
    {  // V: subtiled [dblk][j][16]
      const int dblk = q >> 1;
      const int j = (q & 1) * 32 + (lane >> 1);
      const int dlow = (lane & 1) * 8;
      vOff[qq] = j * EMBED + dblk * 16 + dlow;
    }
  }
  const unsigned short* Kbase = K + (size_t)bb * SEQ * EMBED + hh * HD;
  const unsigned short* Vbase = V + (size_t)bb * SEQ * EMBED + hh * HD;

  // K LDS read offsets (bytes), loop-invariant
  const int swz = (l16 & 7) << 4;
  const int koffB0 = ((0) | (g * 16)) ^ swz;
  const int koffB1 = ((64) | (g * 16)) ^ swz;
  const int krowB = l16 * 128;

#define STAGE(bufidx, tt)                                                              \
  do {                                                                                 \
    const unsigned short* kb_ = Kbase + (size_t)(tt) * 64 * EMBED;                     \
    const unsigned short* vb_ = Vbase + (size_t)(tt) * 64 * EMBED;                     \
    _Pragma("unroll") for (int qq = 0; qq < 2; ++qq) {                                 \
      gll16(kb_ + kOff[qq], (const char*)&Ksm[bufidx][0] + (wid * 2 + qq) * 1024);     \
      gll16(vb_ + vOff[qq], (const char*)&Vsm[bufidx][0] + (wid * 2 + qq) * 1024);     \
    }                                                                                  \
  } while (0)

  // Q B-fragments (col=i=l16, k=g*8+e), hoisted
  short8 qf0, qf1;
  {
    const unsigned short* qp = Q + (size_t)(bb * SEQ + i_base + l16) * EMBED + hh * HD + g * 8;
    qf0 = *reinterpret_cast<const short8*>(qp);
    qf1 = *reinterpret_cast<const short8*>(qp + 32);
  }
  const float c2i = cptr[i_base + l16];  // log2-domain cumsum at this lane's row i

  // decay-skip horizon: precomputed in cumsum_kernel
  const int t_start = tstartTab[hb * 32 + qb];

  // analytic softmax reference: m_t = -c2(tile-end) + BMARG (monotone since c2 decreasing)
  float mc_prev = (t_start == qb) ? c2i : cptr[t_start * 64 + 63];
  float l_ = 0.f;
  f32x4 accd[4] = {};

  STAGE(0, t_start);
  __syncthreads();

  int buf = 0;
  for (int t = t_start; t <= qb; ++t) {
    if (t < qb) STAGE(buf ^ 1, t + 1);  // prefetch; drained by this iter's end barrier
    const int kv0 = t * 64;
    const bool diag = (t == qb);
    const int nj = diag ? (wid + 1) : 4;  // skip fully-masked j-blocks on diagonal

    const float mc_cur = diag ? c2i : cptr[kv0 + 63];
    const float corr = EXP2(mc_cur - mc_prev);  // <= 1; pure function of c2, no reduction
    mc_prev = mc_cur;
    const float mcB = mc_cur - BMARG;

    // S^T = K·Q^T: col=i=l16, row j = jb*16 + g*4 + r. p = 2^(qk*SCL + mcB - c2_j)
    float pf[4][4];
    float lsum = 0.f;
#pragma unroll
    for (int jb = 0; jb < 4; ++jb) {
      if (jb < nj) {
        const char* kbp = (const char*)&Ksm[buf][0] + jb * 2048 + krowB;
        short8 kf0 = *reinterpret_cast<const short8*>(kbp + koffB0);
        short8 kf1 = *reinterpret_cast<const short8*>(kbp + koffB1);
        f32x4 s = {};
        __builtin_amdgcn_s_setprio(1);
        s = __builtin_amdgcn_mfma_f32_16x16x32_bf16(kf0, qf0, s, 0, 0, 0);
        s = __builtin_amdgcn_mfma_f32_16x16x32_bf16(kf1, qf1, s, 0, 0, 0);
        __builtin_amdgcn_s_setprio(0);
        const f32x4 cv = *reinterpret_cast<const f32x4*>(&cptr[kv0 + jb * 16 + g * 4]);
#pragma unroll
        for (int r = 0; r < 4; ++r) {
          float arg = __builtin_fmaf(s[r], SCL, mcB - cv[r]);
          if (diag && jb == wid && (g * 4 + r > l16)) arg = NINF;  // causal mask
          const float pv = EXP2(arg);
          pf[jb][r] = pv;
          lsum += pv;
        }
      } else {
#pragma unroll
        for (int r = 0; r < 4; ++r) pf[jb][r] = 0.f;
      }
    }
    l_ = l_ * corr + lsum;  // lane-local partial (reduced across g at epilogue)
#pragma unroll
    for (int d = 0; d < 4; ++d) accd[d] *= corr;

    // pack P into B-frags via v_cvt_pk_bf16_f32 (k-slot (g,e) -> j = kc*32 + (e>>2)*16 + g*4 + (e&3))
    u32x4 w0, w1;
    w0[0] = cvtpk(pf[0][0], pf[0][1]); w0[1] = cvtpk(pf[0][2], pf[0][3]);
    w0[2] = cvtpk(pf[1][0], pf[1][1]); w0[3] = cvtpk(pf[1][2], pf[1][3]);
    w1[0] = cvtpk(pf[2][0], pf[2][1]); w1[1] = cvtpk(pf[2][2], pf[2][3]);
    w1[2] = cvtpk(pf[3][0], pf[3][1]); w1[3] = cvtpk(pf[3][2], pf[3][3]);
    const short8 pb0 = __builtin_bit_cast(short8, w0);
    const short8 pb1 = __builtin_bit_cast(short8, w1);

    // O^T += V^T · P : A-frags via tr-read (delivers j = jsub*16 + g*4 + r at d = l16)
    const unsigned vb0 = lds_addr(&Vsm[buf][0]) + lane * 8;
#pragma unroll
    for (int db = 0; db < 4; ++db) {
      const unsigned va = vb0 + db * 2048;
      short4v t0, t1, t2, t3;
      TR_READ(t0, va, "0");
      TR_READ(t1, va, "512");
      TR_READ(t2, va, "1024");
      TR_READ(t3, va, "1536");
      asm volatile("s_waitcnt lgkmcnt(0)" ::: "memory");
      __builtin_amdgcn_sched_barrier(0);
      short8 va0, va1;
#pragma unroll
      for (int e = 0; e < 4; ++e) {
        va0[e] = t0[e]; va0[e + 4] = t1[e];
        va1[e] = t2[e]; va1[e + 4] = t3[e];
      }
      __builtin_amdgcn_s_setprio(1);
      accd[db] = __builtin_amdgcn_mfma_f32_16x16x32_bf16(va0, pb0, accd[db], 0, 0, 0);
      accd[db] = __builtin_amdgcn_mfma_f32_16x16x32_bf16(va1, pb1, accd[db], 0, 0, 0);
      __builtin_amdgcn_s_setprio(0);
    }
    if (t < qb) __syncthreads();  // drains vmcnt (stage t+1) + all waves' LDS reads; last iter: none needed
    buf ^= 1;
  }

  // epilogue: reduce l_ across the 4 g-groups (same i=l16), then store O[i][d]
  l_ += __shfl_xor(l_, 16);
  l_ += __shfl_xor(l_, 32);
  const float inv = 1.0f / l_;
  unsigned short* op = O + (size_t)(bb * SEQ + i_base + l16) * EMBED + hh * HD;
#pragma unroll
  for (int db = 0; db < 4; ++db) {
    u32x2 o;
    o[0] = cvtpk(accd[db][0] * inv, accd[db][1] * inv);
    o[1] = cvtpk(accd[db][2] * inv, accd[db][3] * inv);
    *reinterpret_cast<u32x2*>(op + db * 16 + g * 4) = o;
  }
#undef STAGE
}

// ---------------------------------------------------------------- launcher
extern "C" void kernel_launch(void* const* d_in, const int* in_sizes, int n_in,
                              void* d_out, int out_size, void* d_ws, size_t ws_size,
                              hipStream_t stream) {
  const float* x = (const float*)d_in[0];
  const float* Wq = (const float*)d_in[1];
  const float* Wk = (const float*)d_in[2];
  const float* Wv = (const float*)d_in[3];
  const float* Wo = (const float*)d_in[4];
  const float* Wf = (const float*)d_in[5];
  float* out = (float*)d_out;

  char* ws = (char*)d_ws;
  const size_t SZ_X = (size_t)ROWS * EMBED * sizeof(unsigned short);
  const size_t SZ_W = (size_t)EMBED * EMBED * sizeof(unsigned short);
  const size_t SZ_WF = (size_t)NHEAD * EMBED * sizeof(unsigned short);
  unsigned short* xb = (unsigned short*)ws;   ws += SZ_X;
  unsigned short* Wqb = (unsigned short*)ws;  ws += SZ_W;
  unsigned short* Wkb = (unsigned short*)ws;  ws += SZ_W;
  unsigned short* Wvb = (unsigned short*)ws;  ws += SZ_W;
  unsigned short* Wob = (unsigned short*)ws;  ws += SZ_W;
  unsigned short* Wfh = (unsigned short*)ws;  ws += SZ_WF;
  unsigned short* Wfl = (unsigned short*)ws;  ws += SZ_WF;
  unsigned short* Qb = (unsigned short*)ws;   ws += SZ_X;
  unsigned short* Kb = (unsigned short*)ws;   ws += SZ_X;
  unsigned short* Vb = (unsigned short*)ws;   ws += SZ_X;
  unsigned short* attnb = (unsigned short*)ws; ws += SZ_X;
  float* carr = (float*)ws;                   ws += (size_t)BATCH * NHEAD * SEQ * sizeof(float);
  float* qkmax = (float*)ws;                  ws += 64 * sizeof(float);
  int* tstart = (int*)ws;                     ws += 1024 * sizeof(int);

  // cvt: u16x8 vectorized (16B stores), 512x6 grid
  cvt_all_kernel<<<dim3(512, 6), 256, 0, stream>>>(
      x, Wq, Wk, Wv, Wo, Wf, xb, Wqb, Wkb, Wvb, Wob, Wfh, Wfl,
      (unsigned*)qkmax);

  // QKV GEMM (blocks 0..191) + fused gate (blocks 192..255 on the idle CUs)
  gemm256_kernel<<<256, 512, 0, stream>>>(
      xb, Wqb, Wkb, Wvb, Qb, Kb, Vb, (unsigned*)qkmax, x, Wfh, Wfl, carr);

  // cumsum + decay-skip table
  cumsum_kernel<<<BATCH * NHEAD, 64, 0, stream>>>(carr, qkmax, tstart);

  // attention: QBLK=64, 1024 blocks (128 per XCD)
  fa_attn_kernel<<<1024, 256, 0, stream>>>(Qb, Kb, Vb, carr, tstart, attnb);

  // Wo: 64x64 tiles, double-buffered, 1024 blocks = 4 blocks/CU
  gemm_wo_kernel<<<dim3(16, 64), 256, 0, stream>>>(attnb, Wob, out);
}

// Round 17
// 88.615 us; speedup vs baseline: 1.0345x; 1.0345x over previous
//
#include <hip/hip_runtime.h>

// Problem constants
#define EMBED 1024
#define NHEAD 16
#define HD    64
#define SEQ   2048
#define BATCH 2
#define ROWS  (BATCH * SEQ)  // 4096

typedef float f32x4 __attribute__((ext_vector_type(4)));
typedef short short8 __attribute__((ext_vector_type(8)));
typedef short short4v __attribute__((ext_vector_type(4)));
typedef unsigned short u16x4 __attribute__((ext_vector_type(4)));
typedef unsigned short u16x8 __attribute__((ext_vector_type(8)));
typedef unsigned u32x4 __attribute__((ext_vector_type(4)));
typedef unsigned u32x2 __attribute__((ext_vector_type(2)));

#define LOG2E 1.4426950408889634f

__device__ __forceinline__ unsigned short f2bf(float f) {
  unsigned int u = __builtin_bit_cast(unsigned int, f);
  u += 0x7fffu + ((u >> 16) & 1u);  // round-to-nearest-even
  return (unsigned short)(u >> 16);
}

// pack 2 f32 -> 2 bf16 in one u32 (RNE), gfx950
__device__ __forceinline__ unsigned cvtpk(float lo, float hi) {
  unsigned r;
  asm("v_cvt_pk_bf16_f32 %0, %1, %2" : "=v"(r) : "v"(lo), "v"(hi));
  return r;
}

#if __has_builtin(__builtin_amdgcn_exp2f)
#define EXP2(x) __builtin_amdgcn_exp2f(x)
#else
#define EXP2(x) exp2f(x)
#endif

__device__ __forceinline__ void gll16(const void* g, const void* l) {
  __builtin_amdgcn_global_load_lds(
      (const __attribute__((address_space(1))) unsigned int*)g,
      (__attribute__((address_space(3))) unsigned int*)l, 16, 0, 0);
}

__device__ __forceinline__ unsigned lds_addr(const void* p) {
  return (unsigned)(size_t)(__attribute__((address_space(3))) const void*)p;
}

// ---------------------------------------------------------------- cvt (u16x8 vectorized, 16B stores)
// 4 weights (y<4), x->bf16 (y==4), Wf hi+lo + qkmax zero (y==5)
__global__ __launch_bounds__(256) void cvt_all_kernel(
    const float* __restrict__ x,
    const float* __restrict__ w0, const float* __restrict__ w1,
    const float* __restrict__ w2, const float* __restrict__ w3,
    const float* __restrict__ wf,
    unsigned short* __restrict__ xo,
    unsigned short* __restrict__ o0, unsigned short* __restrict__ o1,
    unsigned short* __restrict__ o2, unsigned short* __restrict__ o3,
    unsigned short* __restrict__ wfh, unsigned short* __restrict__ wfl,
    unsigned* __restrict__ qkmaxu) {
  const int y = blockIdx.y;
  if (y < 4) {
    const float* in = (y == 0) ? w0 : (y == 1) ? w1 : (y == 2) ? w2 : w3;
    unsigned short* out = (y == 0) ? o0 : (y == 1) ? o1 : (y == 2) ? o2 : o3;
    const int i = blockIdx.x * 256 + threadIdx.x;  // u16x8 index, 131072 per weight
    const f32x4 v0 = reinterpret_cast<const f32x4*>(in)[2 * i];
    const f32x4 v1 = reinterpret_cast<const f32x4*>(in)[2 * i + 1];
    u16x8 o;
#pragma unroll
    for (int e = 0; e < 4; ++e) { o[e] = f2bf(v0[e]); o[e + 4] = f2bf(v1[e]); }
    reinterpret_cast<u16x8*>(out)[i] = o;
  } else if (y == 4) {
#pragma unroll
    for (int e = 0; e < 4; ++e) {
      const int i = e * 131072 + blockIdx.x * 256 + threadIdx.x;  // u16x8 index, 524288 total
      const f32x4 v0 = reinterpret_cast<const f32x4*>(x)[2 * i];
      const f32x4 v1 = reinterpret_cast<const f32x4*>(x)[2 * i + 1];
      u16x8 h;
#pragma unroll
      for (int q = 0; q < 4; ++q) { h[q] = f2bf(v0[q]); h[q + 4] = f2bf(v1[q]); }
      reinterpret_cast<u16x8*>(xo)[i] = h;
    }
  } else {
    if (blockIdx.x < 8) {
      const int i = blockIdx.x * 256 + threadIdx.x;  // u16x8 index, 2048 total
      const f32x4 v0 = reinterpret_cast<const f32x4*>(wf)[2 * i];
      const f32x4 v1 = reinterpret_cast<const f32x4*>(wf)[2 * i + 1];
      u16x8 h, l;
#pragma unroll
      for (int q = 0; q < 4; ++q) {
        h[q] = f2bf(v0[q]);
        l[q] = f2bf(v0[q] - __builtin_bit_cast(float, (unsigned)h[q] << 16));
        h[q + 4] = f2bf(v1[q]);
        l[q + 4] = f2bf(v1[q] - __builtin_bit_cast(float, (unsigned)h[q + 4] << 16));
      }
      reinterpret_cast<u16x8*>(wfh)[i] = h;
      reinterpret_cast<u16x8*>(wfl)[i] = l;
    } else if (blockIdx.x == 8) {
      if (threadIdx.x < 64) qkmaxu[threadIdx.x] = 0u;  // zero-init for atomicMax (workspace is poisoned)
    }
  }
}

// ---------------------------------------------------------------- Wo GEMM C = A @ B^T, 64x64 tile, BK=64, fp32 out
// 1024 blocks = 4 blocks/CU (LDS 16KB), SINGLE-buffered. R16 lesson: at >=2 blocks/CU the 2-phase
// stall is TLP-hidden; intra-block double-buffering adds a vmcnt drain and REGRESSES (+2.9us).
__global__ __launch_bounds__(256) void gemm_wo_kernel(
    const unsigned short* __restrict__ A, const unsigned short* __restrict__ B,
    float* __restrict__ C) {
  __shared__ unsigned short Asm[64 * 64];
  __shared__ unsigned short Bsm[64 * 64];
  const int tid = threadIdx.x, wid = tid >> 6, lane = tid & 63;
  const int g = lane >> 4, l16 = lane & 15;
  const int wr = wid >> 1, wc = wid & 1;  // wave tile: rows wr*32, cols wc*32
  const int mb = blockIdx.y;              // 64-row tiles (64)
  const int nb = blockIdx.x;              // 64-col tiles (16)

  f32x4 acc[2][2] = {};

  for (int k0 = 0; k0 < EMBED; k0 += 64) {
    __syncthreads();
#pragma unroll
    for (int q = 0; q < 2; ++q) {
      const int base = (wid * 2 + q) * 1024;
      const int off = base + lane * 16;
      const int row = off >> 7;
      const int colel = (off & 127) >> 1;
      gll16(A + (size_t)(mb * 64 + row) * EMBED + k0 + colel, (const char*)Asm + base);
      gll16(B + (size_t)(nb * 64 + row) * EMBED + k0 + colel, (const char*)Bsm + base);
    }
    __syncthreads();

#pragma unroll
    for (int kc = 0; kc < 2; ++kc) {
      short8 am[2], bm[2];
#pragma unroll
      for (int mi = 0; mi < 2; ++mi)
        am[mi] = *reinterpret_cast<const short8*>(&Asm[(wr * 32 + mi * 16 + l16) * 64 + kc * 32 + g * 8]);
#pragma unroll
      for (int ni = 0; ni < 2; ++ni)
        bm[ni] = *reinterpret_cast<const short8*>(&Bsm[(wc * 32 + ni * 16 + l16) * 64 + kc * 32 + g * 8]);
#pragma unroll
      for (int mi = 0; mi < 2; ++mi)
#pragma unroll
        for (int ni = 0; ni < 2; ++ni)
          acc[mi][ni] = __builtin_amdgcn_mfma_f32_16x16x32_bf16(am[mi], bm[ni], acc[mi][ni], 0, 0, 0);
    }
  }

#pragma unroll
  for (int mi = 0; mi < 2; ++mi)
#pragma unroll
    for (int ni = 0; ni < 2; ++ni)
#pragma unroll
      for (int r = 0; r < 4; ++r) {
        const int m = mb * 64 + wr * 32 + mi * 16 + g * 4 + r;
        const int n = nb * 64 + wc * 32 + ni * 16 + l16;
        C[(size_t)m * EMBED + n] = acc[mi][ni][r];
      }
}

// ---------------------------------------------------------------- 256x256 8-phase GEMM + FUSED GATE
// Blocks 0..191: QKV GEMM (best measured of 3 structures; parked). Blocks 192..255: gate.
#define BAR() asm volatile("s_barrier" ::: "memory")
#define LGKM0()                                              \
  do {                                                       \
    asm volatile("s_waitcnt lgkmcnt(0)" ::: "memory");       \
    __builtin_amdgcn_sched_barrier(0);                       \
  } while (0)
#define VM(n_) asm volatile("s_waitcnt vmcnt(" #n_ ")" ::: "memory")

__global__ __launch_bounds__(512, 2) void gemm256_kernel(
    const unsigned short* __restrict__ A,
    const unsigned short* __restrict__ B0, const unsigned short* __restrict__ B1,
    const unsigned short* __restrict__ B2,
    unsigned short* __restrict__ C0, unsigned short* __restrict__ C1,
    unsigned short* __restrict__ C2, unsigned* __restrict__ qkmaxu,
    const float* __restrict__ x, const unsigned short* __restrict__ wfh,
    const unsigned short* __restrict__ wfl, float* __restrict__ carr) {
  __shared__ unsigned short sm[2][2][2][8192];  // [dbuf][AB][half][row*64+col] : 128 KiB
  const int tid = threadIdx.x, wid = tid >> 6, lane = tid & 63;
  const int g = lane >> 4, l16 = lane & 15;

  if (blockIdx.x >= 192) {
    // ---------------- gate branch (runs on the 64 CUs the GEMM grid leaves idle) ----------------
    const int bid2 = blockIdx.x - 192;           // 0..63
    const int tile = bid2 * 4 + (wid >> 1);      // 0..255 (16-row tiles)
    const int half = wid & 1;                    // 2-way split-K
    const int row0 = tile * 16;
    const int k0 = half * 512;
    const float* xp = x + (size_t)(row0 + l16) * EMBED + k0 + g * 8;
    const unsigned short* whp = wfh + (size_t)l16 * EMBED + k0 + g * 8;
    const unsigned short* wlp = wfl + (size_t)l16 * EMBED + k0 + g * 8;
    f32x4 acc = {};
#pragma unroll
    for (int k = 0; k < 16; ++k) {
      const f32x4 v0 = *reinterpret_cast<const f32x4*>(xp + k * 32);
      const f32x4 v1 = *reinterpret_cast<const f32x4*>(xp + k * 32 + 4);
      short8 ah, al;
#pragma unroll
      for (int e = 0; e < 4; ++e) {
        const unsigned short h0 = f2bf(v0[e]);
        ah[e] = (short)h0;
        al[e] = (short)f2bf(v0[e] - __builtin_bit_cast(float, (unsigned)h0 << 16));
        const unsigned short h1 = f2bf(v1[e]);
        ah[e + 4] = (short)h1;
        al[e + 4] = (short)f2bf(v1[e] - __builtin_bit_cast(float, (unsigned)h1 << 16));
      }
      const short8 bh = *reinterpret_cast<const short8*>(whp + k * 32);
      const short8 bl = *reinterpret_cast<const short8*>(wlp + k * 32);
      acc = __builtin_amdgcn_mfma_f32_16x16x32_bf16(ah, bh, acc, 0, 0, 0);
      acc = __builtin_amdgcn_mfma_f32_16x16x32_bf16(ah, bl, acc, 0, 0, 0);
      acc = __builtin_amdgcn_mfma_f32_16x16x32_bf16(al, bh, acc, 0, 0, 0);
    }
    f32x4* red = reinterpret_cast<f32x4*>(sm);  // alias: [8][64] f32x4 = 8KB of the 128KB
    red[wid * 64 + lane] = acc;
    __syncthreads();
    if (half == 0) {
      const f32x4 a = red[wid * 64 + lane] + red[(wid + 1) * 64 + lane];
#pragma unroll
      for (int r = 0; r < 4; ++r) {
        const float s = a[r];
        const float ls = (fminf(s, 0.f) - log1pf(__expf(-fabsf(s)))) * LOG2E;
        const int n = row0 + g * 4 + r;
        const int b = n >> 11, nn = n & (SEQ - 1);
        carr[(size_t)(b * NHEAD + l16) * SEQ + nn] = ls;
      }
    }
    return;
  }

  // ---------------- GEMM branch (blocks 0..191) ----------------
  const int wr = wid >> 2, wcol = wid & 3;  // wave tile: rows wr*128.. , cols wcol*64..
  const int mb = blockIdx.x / 12;
  const int nb = blockIdx.x % 12;  // which = nb>>2, col0 = (nb&3)*256
  const int which = nb >> 2;
  const int col0 = (nb & 3) * 256;
  const unsigned short* Bp = (which == 0) ? B0 : (which == 1) ? B1 : B2;
  unsigned short* Cp = (which == 0) ? C0 : (which == 1) ? C1 : C2;

  // ---- staging invariants (pre-swizzled global source, linear LDS dest) ----
  const int lane8 = lane & 7, laneHi = lane >> 3;
  const int colel = (lane8 ^ laneHi) * 8;  // source col element (inverse swizzle; row&7 == laneHi)
  int soff[2];
#pragma unroll
  for (int q = 0; q < 2; ++q)
    soff[q] = (q * 64 + wid * 8 + laneHi) * EMBED + colel;  // element offset within a half-panel
  const unsigned short* Ag = A + (size_t)(mb * 256) * EMBED;
  const unsigned short* Bg = Bp + (size_t)col0 * EMBED;

  // ---- ds_read invariants (swizzled column offsets; row&7 == l16&7 for all frag rows) ----
  const int sw = (l16 & 7) << 4;
  const int cs0 = (0 | (g * 16)) ^ sw;   // kc=0
  const int cs1 = (64 | (g * 16)) ^ sw;  // kc=1
  const char* smB = (const char*)sm;
  const int aBase = wr * 16384 + l16 * 128;
  const int bBase = 32768 + (wcol >> 1) * 16384 + (wcol & 1) * 8192 + l16 * 128;

#define STG(buf_, ab_, half_, gsrc_, t_)                                               \
  do {                                                                                 \
    const unsigned short* gp_ = (gsrc_) + (size_t)(half_) * (128 * EMBED) + (t_) * 64; \
    char* lp_ = (char*)sm + (buf_) * 65536 + (ab_) * 32768 + (half_) * 16384 + wid * 1024; \
    gll16(gp_ + soff[0], lp_);                                                         \
    gll16(gp_ + soff[1], lp_ + 8192);                                                  \
  } while (0)

#define RD_A(buf_, row_, kc_) \
  (*reinterpret_cast<const short8*>(smB + (buf_) * 65536 + aBase + (row_) * 2048 + ((kc_) ? cs1 : cs0)))
#define RD_B(buf_, row_, kc_) \
  (*reinterpret_cast<const short8*>(smB + (buf_) * 65536 + bBase + (row_) * 2048 + ((kc_) ? cs1 : cs0)))

#define QUAD(mg_, ng_)                                                                   \
  do {                                                                                   \
    __builtin_amdgcn_s_setprio(1);                                                       \
    _Pragma("unroll") for (int kc_ = 0; kc_ < 2; ++kc_)                                  \
      _Pragma("unroll") for (int mi_ = 0; mi_ < 4; ++mi_)                                \
        _Pragma("unroll") for (int nj_ = 0; nj_ < 2; ++nj_)                              \
          acc[(mg_) * 4 + mi_][(ng_) * 2 + nj_] = __builtin_amdgcn_mfma_f32_16x16x32_bf16( \
              fa[mi_][kc_], fb[(ng_) * 2 + nj_][kc_], acc[(mg_) * 4 + mi_][(ng_) * 2 + nj_], 0, 0, 0); \
    __builtin_amdgcn_s_setprio(0);                                                       \
  } while (0)

  // 4 phases of one K-tile: ph1 {12 ds_reads, stage, Q(0,0)}, ph2 {4, stage, Q(0,1)},
  // ph3 {8, stage, Q(1,0)}, ph4 {stage+vmcnt, Q(1,1)}
#define KTILE4(BUF_, STG_P1, STG_P2, STG_P3, STG_P4_VM)                                  \
  do {                                                                                   \
    _Pragma("unroll") for (int mi_ = 0; mi_ < 4; ++mi_) {                                \
      fa[mi_][0] = RD_A(BUF_, mi_, 0);                                                   \
      fa[mi_][1] = RD_A(BUF_, mi_, 1);                                                   \
    }                                                                                    \
    _Pragma("unroll") for (int ni_ = 0; ni_ < 2; ++ni_) {                                \
      fb[ni_][0] = RD_B(BUF_, ni_, 0);                                                   \
      fb[ni_][1] = RD_B(BUF_, ni_, 1);                                                   \
    }                                                                                    \
    STG_P1;                                                                              \
    asm volatile("s_waitcnt lgkmcnt(8)" ::: "memory");                                   \
    BAR();                                                                               \
    LGKM0();                                                                             \
    QUAD(0, 0);                                                                          \
    BAR();                                                                               \
    _Pragma("unroll") for (int ni_ = 0; ni_ < 2; ++ni_) {                                \
      fb[2 + ni_][0] = RD_B(BUF_, 2 + ni_, 0);                                           \
      fb[2 + ni_][1] = RD_B(BUF_, 2 + ni_, 1);                                           \
    }                                                                                    \
    STG_P2;                                                                              \
    BAR();                                                                               \
    LGKM0();                                                                             \
    QUAD(0, 1);                                                                          \
    BAR();                                                                               \
    _Pragma("unroll") for (int mi_ = 0; mi_ < 4; ++mi_) {                                \
      fa[mi_][0] = RD_A(BUF_, 4 + mi_, 0);                                               \
      fa[mi_][1] = RD_A(BUF_, 4 + mi_, 1);                                               \
    }                                                                                    \
    STG_P3;                                                                              \
    BAR();                                                                               \
    LGKM0();                                                                             \
    QUAD(1, 0);                                                                          \
    BAR();                                                                               \
    STG_P4_VM;                                                                           \
    BAR();                                                                               \
    QUAD(1, 1);                                                                          \
    BAR();                                                                               \
  } while (0)

  short8 fa[4][2], fb[4][2];
  f32x4 acc[8][4] = {};

  // ---- prologue: tile0 fully (A0,B0,A1,B1) + tile1 B-halves; wait tile0, keep 2 halves in flight ----
  STG(0, 0, 0, Ag, 0);
  STG(0, 1, 0, Bg, 0);
  STG(0, 0, 1, Ag, 0);
  STG(0, 1, 1, Bg, 0);
  STG(1, 1, 0, Bg, 1);
  STG(1, 1, 1, Bg, 1);
  VM(4);
  BAR();

  // ---- main loop: 16 K-tiles, 2 per iteration (buf0 then buf1), 8 phases ----
  for (int it = 0; it < 8; ++it) {
    const int t1 = 2 * it + 1, t2 = 2 * it + 2, t3 = 2 * it + 3;
    const bool nl = (it < 7);
    // K-tile 2i (buf0); stage t1's A-halves (buf1) then t2's B-halves (buf0, released after ph2)
    KTILE4(0,
           STG(1, 0, 0, Ag, t1),
           STG(1, 0, 1, Ag, t1),
           if (nl) STG(0, 1, 0, Bg, t2),
           if (nl) { STG(0, 1, 1, Bg, t2); VM(4); } else VM(0));
    // K-tile 2i+1 (buf1); stage t2's A-halves (buf0, released after ph3) then t3's B-halves (buf1)
    KTILE4(1,
           if (nl) STG(0, 0, 0, Ag, t2),
           if (nl) STG(0, 0, 1, Ag, t2),
           if (nl) STG(1, 1, 0, Bg, t3),
           if (nl) { STG(1, 1, 1, Bg, t3); VM(4); });
  }

  // ---- epilogue (+ fused maxabs for Q/K tensors) ----
  unsigned mxv = 0;
#pragma unroll
  for (int mi = 0; mi < 8; ++mi)
#pragma unroll
    for (int ni = 0; ni < 4; ++ni)
#pragma unroll
      for (int r = 0; r < 4; ++r) {
        const int m = mb * 256 + wr * 128 + mi * 16 + g * 4 + r;
        const int n = col0 + wcol * 64 + ni * 16 + l16;
        const unsigned short bv = f2bf(acc[mi][ni][r]);
        Cp[(size_t)m * EMBED + n] = bv;
        const unsigned a = bv & 0x7fffu;
        mxv = a > mxv ? a : mxv;
      }
  if (which < 2) {
#pragma unroll
    for (int mm = 1; mm < 64; mm <<= 1) {
      const unsigned o = __shfl_xor(mxv, mm);
      mxv = o > mxv ? o : mxv;
    }
    if (lane == 0) {
      const int bbat = (mb >= 8) ? 1 : 0;
      const int head = (nb & 3) * 4 + wcol;
      const int idx = which * 32 + bbat * 16 + head;
      atomicMax(&qkmaxu[idx], mxv << 16);  // positive-float bits: uint max == float max
    }
  }
#undef STG
#undef RD_A
#undef RD_B
#undef QUAD
#undef KTILE4
}
#undef BAR
#undef LGKM0
#undef VM

// ---------------------------------------------------------------- cumsum per (b,h) + decay-skip table
__global__ void cumsum_kernel(float* __restrict__ c, const float* __restrict__ qkmax,
                              int* __restrict__ tstart) {
  __shared__ float tendS[32];    // tendS[t-1] = c2[t*64-1]
  __shared__ float cfirstS[32];  // cfirstS[qb] = c2[qb*64]
  const int bh = blockIdx.x;
  const int lane = threadIdx.x;  // 64
  float* p = c + (size_t)bh * SEQ;
  f32x4 vv[8];
  f32x4* vp = reinterpret_cast<f32x4*>(p + lane * 32);
#pragma unroll
  for (int q = 0; q < 8; ++q) vv[q] = vp[q];
  float run = 0.f;
#pragma unroll
  for (int q = 0; q < 8; ++q)
#pragma unroll
    for (int e = 0; e < 4; ++e) { run += vv[q][e]; vv[q][e] = run; }
  float s = run;
#pragma unroll
  for (int off = 1; off < 64; off <<= 1) {
    float u = __shfl_up(s, off);
    if (lane >= off) s += u;
  }
  const float excl = s - run;
#pragma unroll
  for (int q = 0; q < 8; ++q)
#pragma unroll
    for (int e = 0; e < 4; ++e) vv[q][e] += excl;
#pragma unroll
  for (int q = 0; q < 8; ++q) vp[q] = vv[q];

  // decay-skip table
  if (lane & 1) tendS[lane >> 1] = s;            // lane 2t-1 -> tendS[t-1], t=1..32
  else cfirstS[lane >> 1] = vv[0][0];            // lane 2qb  -> cfirstS[qb]
  __syncthreads();
  if (lane < 32) {
    const float qm = qkmax[bh];
    const float km = qkmax[32 + bh];
    const float thr = -41.f - 23.0832f * qm * km;  // -41 - 2U, U = 64*0.125*LOG2E*qm*km
    const float c2imin = cfirstS[lane];
    int t = lane;
    while (t > 0 && (c2imin - tendS[t - 1] >= thr)) --t;
    tstart[bh * 32 + lane] = t;
  }
}

// ---------------------------------------------------------------- flash attention, swapped-QK^T, XCD-clustered
#define NINF (-3.0e38f)
#define SCL (0.125f * LOG2E)
#define BMARG 14.0f

#define TR_READ(dst, addr, OFF) \
  asm volatile("ds_read_b64_tr_b16 %0, %1 offset:" OFF : "=v"(dst) : "v"(addr))

__global__ __launch_bounds__(256) void fa_attn_kernel(
    const unsigned short* __restrict__ Q, const unsigned short* __restrict__ K,
    const unsigned short* __restrict__ V, const float* __restrict__ C,
    const int* __restrict__ tstartTab, unsigned short* __restrict__ O) {
  __shared__ unsigned short Ksm[2][4096];  // 8KB each: [64 j][64 dh], rows XOR-swizzled
  __shared__ unsigned short Vsm[2][4096];  // 8KB each: [4 dblk][64 j][16 d] subtiled
  const int p = blockIdx.x;                 // 0..1023
  const int xcd = p & 7, s2 = p >> 3;       // 128 blocks per XCD
  const int hb = xcd * 4 + (s2 >> 5);       // (b,h) pair index (4 per XCD -> 2MB L2 set)
  const int qb = s2 & 31;
  const int hh = hb & 15, bb = hb >> 4;
  const int tid = threadIdx.x, wid = tid >> 6, lane = tid & 63;
  const int g = lane >> 4, l16 = lane & 15;
  const int i_base = qb * 64 + wid * 16;

  const float* cptr = C + (size_t)(bb * NHEAD + hh) * SEQ;

  // staging source offsets (elements, relative to tile origin), per lane
  int kOff[2], vOff[2];
#pragma unroll
  for (int qq = 0; qq < 2; ++qq) {
    const int q = wid * 2 + qq;
    {  // K: linear LDS pos pl = q*1024 + lane*16 -> row = pl>>7, swizzled source col
      const int row = q * 8 + (lane >> 3);
      const int colel = ((lane & 7) ^ (lane >> 3)) * 8;
      kOff[qq] = row * EMBED + colel;
    }
    {  // V: subtiled [dblk][j][16]
      const int dblk = q >> 1;
      const int j = (q & 1) * 32 + (lane >> 1);
      const int dlow = (lane & 1) * 8;
      vOff[qq] = j * EMBED + dblk * 16 + dlow;
    }
  }
  const unsigned short* Kbase = K + (size_t)bb * SEQ * EMBED + hh * HD;
  const unsigned short* Vbase = V + (size_t)bb * SEQ * EMBED + hh * HD;

  // K LDS read offsets (bytes), loop-invariant
  const int swz = (l16 & 7) << 4;
  const int koffB0 = ((0) | (g * 16)) ^ swz;
  const int koffB1 = ((64) | (g * 16)) ^ swz;
  const int krowB = l16 * 128;

#define STAGE(bufidx, tt)                                                              \
  do {                                                                                 \
    const unsigned short* kb_ = Kbase + (size_t)(tt) * 64 * EMBED;                     \
    const unsigned short* vb_ = Vbase + (size_t)(tt) * 64 * EMBED;                     \
    _Pragma("unroll") for (int qq = 0; qq < 2; ++qq) {                                 \
      gll16(kb_ + kOff[qq], (const char*)&Ksm[bufidx][0] + (wid * 2 + qq) * 1024);     \
      gll16(vb_ + vOff[qq], (const char*)&Vsm[bufidx][0] + (wid * 2 + qq) * 1024);     \
    }                                                                                  \
  } while (0)

  // Q B-fragments (col=i=l16, k=g*8+e), hoisted
  short8 qf0, qf1;
  {
    const unsigned short* qp = Q + (size_t)(bb * SEQ + i_base + l16) * EMBED + hh * HD + g * 8;
    qf0 = *reinterpret_cast<const short8*>(qp);
    qf1 = *reinterpret_cast<const short8*>(qp + 32);
  }
  const float c2i = cptr[i_base + l16];  // log2-domain cumsum at this lane's row i

  // decay-skip horizon: precomputed in cumsum_kernel
  const int t_start = tstartTab[hb * 32 + qb];

  // analytic softmax reference: m_t = -c2(tile-end) + BMARG (monotone since c2 decreasing)
  float mc_prev = (t_start == qb) ? c2i : cptr[t_start * 64 + 63];
  float l_ = 0.f;
  f32x4 accd[4] = {};

  STAGE(0, t_start);
  __syncthreads();

  int buf = 0;
  for (int t = t_start; t <= qb; ++t) {
    if (t < qb) STAGE(buf ^ 1, t + 1);  // prefetch; drained by this iter's end barrier
    const int kv0 = t * 64;
    const bool diag = (t == qb);
    const int nj = diag ? (wid + 1) : 4;  // skip fully-masked j-blocks on diagonal

    const float mc_cur = diag ? c2i : cptr[kv0 + 63];
    const float corr = EXP2(mc_cur - mc_prev);  // <= 1; pure function of c2, no reduction
    mc_prev = mc_cur;
    const float mcB = mc_cur - BMARG;

    // S^T = K·Q^T: col=i=l16, row j = jb*16 + g*4 + r. p = 2^(qk*SCL + mcB - c2_j)
    float pf[4][4];
    float lsum = 0.f;
#pragma unroll
    for (int jb = 0; jb < 4; ++jb) {
      if (jb < nj) {
        const char* kbp = (const char*)&Ksm[buf][0] + jb * 2048 + krowB;
        short8 kf0 = *reinterpret_cast<const short8*>(kbp + koffB0);
        short8 kf1 = *reinterpret_cast<const short8*>(kbp + koffB1);
        f32x4 s = {};
        __builtin_amdgcn_s_setprio(1);
        s = __builtin_amdgcn_mfma_f32_16x16x32_bf16(kf0, qf0, s, 0, 0, 0);
        s = __builtin_amdgcn_mfma_f32_16x16x32_bf16(kf1, qf1, s, 0, 0, 0);
        __builtin_amdgcn_s_setprio(0);
        const f32x4 cv = *reinterpret_cast<const f32x4*>(&cptr[kv0 + jb * 16 + g * 4]);
#pragma unroll
        for (int r = 0; r < 4; ++r) {
          float arg = __builtin_fmaf(s[r], SCL, mcB - cv[r]);
          if (diag && jb == wid && (g * 4 + r > l16)) arg = NINF;  // causal mask
          const float pv = EXP2(arg);
          pf[jb][r] = pv;
          lsum += pv;
        }
      } else {
#pragma unroll
        for (int r = 0; r < 4; ++r) pf[jb][r] = 0.f;
      }
    }
    l_ = l_ * corr + lsum;  // lane-local partial (reduced across g at epilogue)
#pragma unroll
    for (int d = 0; d < 4; ++d) accd[d] *= corr;

    // pack P into B-frags via v_cvt_pk_bf16_f32 (k-slot (g,e) -> j = kc*32 + (e>>2)*16 + g*4 + (e&3))
    u32x4 w0, w1;
    w0[0] = cvtpk(pf[0][0], pf[0][1]); w0[1] = cvtpk(pf[0][2], pf[0][3]);
    w0[2] = cvtpk(pf[1][0], pf[1][1]); w0[3] = cvtpk(pf[1][2], pf[1][3]);
    w1[0] = cvtpk(pf[2][0], pf[2][1]); w1[1] = cvtpk(pf[2][2], pf[2][3]);
    w1[2] = cvtpk(pf[3][0], pf[3][1]); w1[3] = cvtpk(pf[3][2], pf[3][3]);
    const short8 pb0 = __builtin_bit_cast(short8, w0);
    const short8 pb1 = __builtin_bit_cast(short8, w1);

    // O^T += V^T · P : A-frags via tr-read (delivers j = jsub*16 + g*4 + r at d = l16)
    const unsigned vb0 = lds_addr(&Vsm[buf][0]) + lane * 8;
#pragma unroll
    for (int db = 0; db < 4; ++db) {
      const unsigned va = vb0 + db * 2048;
      short4v t0, t1, t2, t3;
      TR_READ(t0, va, "0");
      TR_READ(t1, va, "512");
      TR_READ(t2, va, "1024");
      TR_READ(t3, va, "1536");
      asm volatile("s_waitcnt lgkmcnt(0)" ::: "memory");
      __builtin_amdgcn_sched_barrier(0);
      short8 va0, va1;
#pragma unroll
      for (int e = 0; e < 4; ++e) {
        va0[e] = t0[e]; va0[e + 4] = t1[e];
        va1[e] = t2[e]; va1[e + 4] = t3[e];
      }
      __builtin_amdgcn_s_setprio(1);
      accd[db] = __builtin_amdgcn_mfma_f32_16x16x32_bf16(va0, pb0, accd[db], 0, 0, 0);
      accd[db] = __builtin_amdgcn_mfma_f32_16x16x32_bf16(va1, pb1, accd[db], 0, 0, 0);
      __builtin_amdgcn_s_setprio(0);
    }
    if (t < qb) __syncthreads();  // drains vmcnt (stage t+1) + all waves' LDS reads; last iter: none needed
    buf ^= 1;
  }

  // epilogue: reduce l_ across the 4 g-groups (same i=l16), then store O[i][d]
  l_ += __shfl_xor(l_, 16);
  l_ += __shfl_xor(l_, 32);
  const float inv = 1.0f / l_;
  unsigned short* op = O + (size_t)(bb * SEQ + i_base + l16) * EMBED + hh * HD;
#pragma unroll
  for (int db = 0; db < 4; ++db) {
    u32x2 o;
    o[0] = cvtpk(accd[db][0] * inv, accd[db][1] * inv);
    o[1] = cvtpk(accd[db][2] * inv, accd[db][3] * inv);
    *reinterpret_cast<u32x2*>(op + db * 16 + g * 4) = o;
  }
#undef STAGE
}

// ---------------------------------------------------------------- launcher
extern "C" void kernel_launch(void* const* d_in, const int* in_sizes, int n_in,
                              void* d_out, int out_size, void* d_ws, size_t ws_size,
                              hipStream_t stream) {
  const float* x = (const float*)d_in[0];
  const float* Wq = (const float*)d_in[1];
  const float* Wk = (const float*)d_in[2];
  const float* Wv = (const float*)d_in[3];
  const float* Wo = (const float*)d_in[4];
  const float* Wf = (const float*)d_in[5];
  float* out = (float*)d_out;

  char* ws = (char*)d_ws;
  const size_t SZ_X = (size_t)ROWS * EMBED * sizeof(unsigned short);
  const size_t SZ_W = (size_t)EMBED * EMBED * sizeof(unsigned short);
  const size_t SZ_WF = (size_t)NHEAD * EMBED * sizeof(unsigned short);
  unsigned short* xb = (unsigned short*)ws;   ws += SZ_X;
  unsigned short* Wqb = (unsigned short*)ws;  ws += SZ_W;
  unsigned short* Wkb = (unsigned short*)ws;  ws += SZ_W;
  unsigned short* Wvb = (unsigned short*)ws;  ws += SZ_W;
  unsigned short* Wob = (unsigned short*)ws;  ws += SZ_W;
  unsigned short* Wfh = (unsigned short*)ws;  ws += SZ_WF;
  unsigned short* Wfl = (unsigned short*)ws;  ws += SZ_WF;
  unsigned short* Qb = (unsigned short*)ws;   ws += SZ_X;
  unsigned short* Kb = (unsigned short*)ws;   ws += SZ_X;
  unsigned short* Vb = (unsigned short*)ws;   ws += SZ_X;
  unsigned short* attnb = (unsigned short*)ws; ws += SZ_X;
  float* carr = (float*)ws;                   ws += (size_t)BATCH * NHEAD * SEQ * sizeof(float);
  float* qkmax = (float*)ws;                  ws += 64 * sizeof(float);
  int* tstart = (int*)ws;                     ws += 1024 * sizeof(int);

  // cvt: u16x8 vectorized (16B stores), 512x6 grid
  cvt_all_kernel<<<dim3(512, 6), 256, 0, stream>>>(
      x, Wq, Wk, Wv, Wo, Wf, xb, Wqb, Wkb, Wvb, Wob, Wfh, Wfl,
      (unsigned*)qkmax);

  // QKV GEMM (blocks 0..191) + fused gate (blocks 192..255 on the idle CUs)
  gemm256_kernel<<<256, 512, 0, stream>>>(
      xb, Wqb, Wkb, Wvb, Qb, Kb, Vb, (unsigned*)qkmax, x, Wfh, Wfl, carr);

  // cumsum + decay-skip table
  cumsum_kernel<<<BATCH * NHEAD, 64, 0, stream>>>(carr, qkmax, tstart);

  // attention: QBLK=64, 1024 blocks (128 per XCD)
  fa_attn_kernel<<<1024, 256, 0, stream>>>(Qb, Kb, Vb, carr, tstart, attnb);

  // Wo: 64x64 tiles, single-buffered, 1024 blocks = 4 blocks/CU
  gemm_wo_kernel<<<dim3(16, 64), 256, 0, stream>>>(attnb, Wob, out);
}